// Round 1
// baseline (40066.275 us; speedup 1.0000x reference)
//
#include <hip/hip_runtime.h>
#include <hip/hip_bf16.h>
#include <math.h>
#include <stddef.h>

namespace {

constexpr int V = 32000, H = 512, L = 4, A = 384, B = 2, T = 32, FF = 2048;
constexpr int GH = H - A;                 // 128 ghost rows
constexpr long LOGITS = (long)B * T * V;  // 2,048,000
constexpr int GRID = 256, NT = 256;
constexpr float EPS = 1e-5f;

struct WS {
  unsigned bar_cnt, bar_gen;
  unsigned pad[30];
  float xbuf[2][B * H];
  float colsum[2][B * H];
  float ghost[B * GH * H];   // recur-1 intermediate ghost rows
  float outs[T * B * H];
  float lnouts[T * B * H];
};

union __align__(16) SMem {
  struct { float rows[8 * H]; float csum[96]; } gp;
  struct { float x[H], lnx[H], u[A], bu[A], v[64], bv[64], red[64], part[256]; } t1;
  struct { float xmid[H], lnx[H], red[64], part[256], h1[32]; } ffn;
  struct { float row[H], red[64]; } lnr;
  struct { float rows[32 * H]; } head;   // 64 KiB
};

__device__ __forceinline__ float blk_sum(float v, float* red) {
  #pragma unroll
  for (int o = 32; o; o >>= 1) v += __shfl_down(v, o, 64);
  int w = threadIdx.x >> 6;
  __syncthreads();
  if ((threadIdx.x & 63) == 0) red[w] = v;
  __syncthreads();
  return red[0] + red[1] + red[2] + red[3];
}

__device__ void gbar(WS* ws) {
  __syncthreads();
  if (threadIdx.x == 0) {
    __threadfence();
    unsigned g = __hip_atomic_load(&ws->bar_gen, __ATOMIC_RELAXED, __HIP_MEMORY_SCOPE_AGENT);
    unsigned a = __hip_atomic_fetch_add(&ws->bar_cnt, 1u, __ATOMIC_ACQ_REL, __HIP_MEMORY_SCOPE_AGENT);
    if (a == (unsigned)(gridDim.x - 1)) {
      __hip_atomic_store(&ws->bar_cnt, 0u, __ATOMIC_RELAXED, __HIP_MEMORY_SCOPE_AGENT);
      __hip_atomic_fetch_add(&ws->bar_gen, 1u, __ATOMIC_RELEASE, __HIP_MEMORY_SCOPE_AGENT);
    } else {
      while (__hip_atomic_load(&ws->bar_gen, __ATOMIC_ACQUIRE, __HIP_MEMORY_SCOPE_AGENT) == g)
        __builtin_amdgcn_s_sleep(1);
    }
    __threadfence();
  }
  __syncthreads();
}

// One ghost-matmul tile: w in [0,224): (b, g-tile of 8 rows, o-range ~73).
// dst[b, g, o] = src[b, g, o] + sigmoid(src_row . Wg[o]) * tanh(src_row . Wt[o])
__device__ void ghost_phase(int w, const float* __restrict__ src0, long sbs,
                            float* __restrict__ dst0, long dbs,
                            const float* __restrict__ Wg, const float* __restrict__ Wt,
                            float* colsum, SMem* sm) {
  int b = w / 112, r = w % 112;
  int gt = r / 7, ot = r % 7;
  int g0 = gt * 8;
  int o0 = (ot * H) / 7, o1 = ((ot + 1) * H) / 7, osz = o1 - o0;
  const float* src = src0 + (long)b * sbs + (long)g0 * H;   // 8 contiguous rows
  for (int idx = threadIdx.x; idx < 8 * (H / 4); idx += NT)
    ((float4*)sm->gp.rows)[idx] = ((const float4*)src)[idx];
  for (int i = threadIdx.x; i < osz; i += NT) sm->gp.csum[i] = 0.f;
  __syncthreads();
  int npair = 8 * osz;
  for (int pp = threadIdx.x; pp < npair; pp += NT) {
    int g = pp / osz, o_l = pp - g * osz, o = o0 + o_l;
    const float* wg = Wg + (long)o * H;
    const float* wt = Wt + (long)o * H;
    const float* gr = sm->gp.rows + g * H;
    float ag = 0.f, at = 0.f;
    for (int k = 0; k < H; k += 4) {
      float4 x = *(const float4*)(gr + k);
      float4 yg = *(const float4*)(wg + k);
      float4 yt = *(const float4*)(wt + k);
      ag += x.x * yg.x + x.y * yg.y + x.z * yg.z + x.w * yg.w;
      at += x.x * yt.x + x.y * yt.y + x.z * yt.z + x.w * yt.w;
    }
    float up = (1.f / (1.f + expf(-ag))) * tanhf(at);
    float val = sm->gp.rows[g * H + o] + up;
    dst0[(long)b * dbs + (long)(g0 + g) * H + o] = val;
    if (colsum) atomicAdd(&sm->gp.csum[o_l], val);
  }
  if (colsum) {
    __syncthreads();
    for (int i = threadIdx.x; i < osz; i += NT)
      atomicAdd(&colsum[b * H + o0 + i], sm->gp.csum[i]);
  }
}

__global__ __launch_bounds__(NT) void vega_kernel(
    const int* __restrict__ ids, const float* __restrict__ emb,
    const float* __restrict__ nx_w, const float* __restrict__ nx_b,
    const float* __restrict__ Wp, const float* __restrict__ bp,
    const float* __restrict__ Wg, const float* __restrict__ Wt,
    const float* __restrict__ ns_w, const float* __restrict__ ns_b,
    const float* __restrict__ W1, const float* __restrict__ b1,
    const float* __restrict__ W2, const float* __restrict__ b2,
    const float* __restrict__ on_w, const float* __restrict__ on_b,
    const float* __restrict__ head_W, const float* __restrict__ head_b,
    float* __restrict__ out, WS* ws) {
  __shared__ SMem sm;
  float* state = out + LOGITS;  // (L,B,H,H), pre-copied from input states
  const int bid = blockIdx.x, tid = threadIdx.x;

  for (int t = 0; t < T; ++t) {
    for (int l = 0; l < L; ++l) {
      const int s = t * L + l, p = s & 1;
      float* xout = (l == L - 1) ? ws->outs + (long)t * B * H : ws->xbuf[p ^ 1];

      // ---------------- PHASE A: recur-1 ghost matmul + active update ----------------
      if (bid < 224) {
        ghost_phase(bid, state + ((long)(l * B) * H + A) * H, (long)H * H,
                    ws->ghost, (long)GH * H,
                    Wg + (long)l * H * H, Wt + (long)l * H * H, nullptr, &sm);
      } else if (bid < 240) {
        // active rows: state += u(x)ov + bu(x)obv  (recur-2 active term is the
        // constant bias outer product since its input is zero); owns colsum cols.
        int q = bid - 224, b = q >> 3, jt = q & 7;
        const float* xin = (l == 0) ? emb + (long)ids[b * T + t] * H : ws->xbuf[p] + b * H;
        sm.t1.x[tid] = xin[tid];
        sm.t1.x[tid + 256] = xin[tid + 256];
        __syncthreads();
        float lm = blk_sum(sm.t1.x[tid] + sm.t1.x[tid + 256], sm.t1.red) * (1.f / H);
        float d0 = sm.t1.x[tid] - lm, d1 = sm.t1.x[tid + 256] - lm;
        float var = blk_sum(d0 * d0 + d1 * d1, sm.t1.red) * (1.f / H);
        float inv = rsqrtf(var + EPS);
        sm.t1.lnx[tid]       = d0 * inv * nx_w[l * H + tid] + nx_b[l * H + tid];
        sm.t1.lnx[tid + 256] = d1 * inv * nx_w[l * H + tid + 256] + nx_b[l * H + tid + 256];
        __syncthreads();
        const float* WpL = Wp + (long)l * (A + H) * H;
        const float* bpL = bp + (long)l * (A + H);
        for (int q2 = tid; q2 < A + 64; q2 += NT) {
          int row = (q2 < A) ? q2 : (A + jt * 64 + (q2 - A));
          float acc = bpL[row];
          const float* wr = WpL + (long)row * H;
          for (int k = 0; k < H; k += 4) {
            float4 x = *(const float4*)(sm.t1.lnx + k);
            float4 y = *(const float4*)(wr + k);
            acc += x.x * y.x + x.y * y.y + x.z * y.z + x.w * y.w;
          }
          if (q2 < A) { sm.t1.u[q2] = acc; sm.t1.bu[q2] = bpL[q2]; }
          else { int j = q2 - A; sm.t1.v[j] = acc; sm.t1.bv[j] = bpL[row]; }
        }
        __syncthreads();
        int j_l = tid & 63, ig = tid >> 6;
        int jg = jt * 64 + j_l;
        float* sp = state + ((long)(l * B + b) * H) * H + jg;
        float vj = sm.t1.v[j_l], bvj = sm.t1.bv[j_l];
        float accc = 0.f;
        for (int i = ig * 96; i < ig * 96 + 96; ++i) {
          float val = sp[(long)i * H] + sm.t1.u[i] * vj + sm.t1.bu[i] * bvj;
          sp[(long)i * H] = val;
          accc += val;
        }
        sm.t1.part[ig * 64 + j_l] = accc;
        __syncthreads();
        if (tid < 64) {
          float ssum = sm.t1.part[tid] + sm.t1.part[64 + tid] +
                       sm.t1.part[128 + tid] + sm.t1.part[192 + tid];
          ws->colsum[p][b * H + jt * 64 + tid] = ssum;  // exclusive owner this phase
        }
      } else if (bid == 240) {
        for (int i = tid; i < B * H; i += NT) xout[i] = 0.f;  // FFN scatter target
      }
      gbar(ws);

      // ---------------- PHASE B: recur-2 ghost matmul + ghost colsums ----------------
      if (bid < 224) {
        ghost_phase(bid, ws->ghost, (long)GH * H,
                    state + ((long)(l * B) * H + A) * H, (long)H * H,
                    Wg + (long)l * H * H, Wt + (long)l * H * H, ws->colsum[p], &sm);
      }
      gbar(ws);

      // ---------------- PHASE C: x += mean, LN, FFN (fused scatter) ----------------
      if (bid < 128) {
        int b = bid >> 6, ft = bid & 63;  // 64 f-tiles of 32
        const float* xin = (l == 0) ? emb + (long)ids[b * T + t] * H : ws->xbuf[p] + b * H;
        const float* cs = ws->colsum[p] + b * H;
        sm.ffn.xmid[tid]       = xin[tid] + cs[tid] * (1.f / H);
        sm.ffn.xmid[tid + 256] = xin[tid + 256] + cs[tid + 256] * (1.f / H);
        __syncthreads();
        float m = blk_sum(sm.ffn.xmid[tid] + sm.ffn.xmid[tid + 256], sm.ffn.red) * (1.f / H);
        float d0 = sm.ffn.xmid[tid] - m, d1 = sm.ffn.xmid[tid + 256] - m;
        float var = blk_sum(d0 * d0 + d1 * d1, sm.ffn.red) * (1.f / H);
        float inv = rsqrtf(var + EPS);
        sm.ffn.lnx[tid]       = d0 * inv * ns_w[l * H + tid] + ns_b[l * H + tid];
        sm.ffn.lnx[tid + 256] = d1 * inv * ns_w[l * H + tid + 256] + ns_b[l * H + tid + 256];
        __syncthreads();
        int f_l = tid & 31, kg = tid >> 5;  // 8 k-groups of 64
        {
          const float* w1r = W1 + ((long)l * FF + ft * 32 + f_l) * H + kg * 64;
          const float* lx = sm.ffn.lnx + kg * 64;
          float partial = 0.f;
          for (int k = 0; k < 64; k += 4) {
            float4 x = *(const float4*)(lx + k);
            float4 y = *(const float4*)(w1r + k);
            partial += x.x * y.x + x.y * y.y + x.z * y.z + x.w * y.w;
          }
          sm.ffn.part[kg * 32 + f_l] = partial;
        }
        __syncthreads();
        if (tid < 32) {
          float ssum = 0.f;
          #pragma unroll
          for (int j = 0; j < 8; ++j) ssum += sm.ffn.part[j * 32 + tid];
          float z = ssum + b1[(long)l * FF + ft * 32 + tid];
          sm.ffn.h1[tid] = 0.5f * z * (1.f + erff(z * 0.70710678118f));  // exact gelu
        }
        __syncthreads();
        #pragma unroll
        for (int rep = 0; rep < 2; ++rep) {
          int o = tid + rep * 256;
          const float* w2r = W2 + ((long)l * H + o) * FF + ft * 32;
          float contrib = 0.f;
          for (int fl = 0; fl < 32; fl += 4) {
            float4 y = *(const float4*)(w2r + fl);
            contrib += sm.ffn.h1[fl] * y.x + sm.ffn.h1[fl + 1] * y.y +
                       sm.ffn.h1[fl + 2] * y.z + sm.ffn.h1[fl + 3] * y.w;
          }
          if (ft == 0) contrib += sm.ffn.xmid[o] + b2[l * H + o];
          atomicAdd(&xout[b * H + o], contrib);
        }
      } else if (bid == 128) {
        for (int i = tid; i < B * H; i += NT) ws->colsum[p ^ 1][i] = 0.f;
      }
      gbar(ws);
    }
  }

  // ---------------- Final LN of the 64 output rows ----------------
  if (bid < T * B) {
    const float* row = ws->outs + (long)bid * H;
    sm.lnr.row[tid] = row[tid];
    sm.lnr.row[tid + 256] = row[tid + 256];
    __syncthreads();
    float m = blk_sum(sm.lnr.row[tid] + sm.lnr.row[tid + 256], sm.lnr.red) * (1.f / H);
    float d0 = sm.lnr.row[tid] - m, d1 = sm.lnr.row[tid + 256] - m;
    float var = blk_sum(d0 * d0 + d1 * d1, sm.lnr.red) * (1.f / H);
    float inv = rsqrtf(var + EPS);
    ws->lnouts[(long)bid * H + tid]       = d0 * inv * on_w[tid] + on_b[tid];
    ws->lnouts[(long)bid * H + tid + 256] = d1 * inv * on_w[tid + 256] + on_b[tid + 256];
  }
  gbar(ws);

  // ---------------- Head GEMM: 64 rows x 32000 vocab, K=512 ----------------
  if (bid < 250) {
    int v = bid * 128 + (tid & 127);
    int half = tid >> 7;
    const float* wv = head_W + (long)v * H;
    float hb = head_b[v];
    for (int pass = 0; pass < 2; ++pass) {
      __syncthreads();
      for (int idx = tid; idx < 32 * (H / 4); idx += NT)
        ((float4*)sm.head.rows)[idx] = ((const float4*)(ws->lnouts + (long)pass * 32 * H))[idx];
      __syncthreads();
      float acc[16];
      #pragma unroll
      for (int i = 0; i < 16; ++i) acc[i] = 0.f;
      const float* lbase = sm.head.rows + half * 16 * H;
      for (int k = 0; k < H; k += 4) {
        float4 y = *(const float4*)(wv + k);
        #pragma unroll
        for (int i = 0; i < 16; ++i) {
          float4 x = *(const float4*)(lbase + i * H + k);
          acc[i] += x.x * y.x + x.y * y.y + x.z * y.z + x.w * y.w;
        }
      }
      #pragma unroll
      for (int i = 0; i < 16; ++i) {
        int rr = pass * 32 + half * 16 + i;
        int tt = rr >> 1, b = rr & 1;
        out[((long)b * T + tt) * V + v] = acc[i] + hb;
      }
    }
  }
}

}  // namespace

extern "C" void kernel_launch(void* const* d_in, const int* in_sizes, int n_in,
                              void* d_out, int out_size, void* d_ws, size_t ws_size,
                              hipStream_t stream) {
  (void)in_sizes; (void)n_in; (void)out_size; (void)ws_size;
  const int*   ids    = (const int*)d_in[0];
  const float* states = (const float*)d_in[1];
  const float* emb    = (const float*)d_in[2];
  const float* nx_w   = (const float*)d_in[3];
  const float* nx_b   = (const float*)d_in[4];
  const float* Wp     = (const float*)d_in[5];
  const float* bp     = (const float*)d_in[6];
  const float* Wg     = (const float*)d_in[7];
  const float* Wt     = (const float*)d_in[8];
  const float* ns_w   = (const float*)d_in[9];
  const float* ns_b   = (const float*)d_in[10];
  const float* W1     = (const float*)d_in[11];
  const float* b1     = (const float*)d_in[12];
  const float* W2     = (const float*)d_in[13];
  const float* b2     = (const float*)d_in[14];
  const float* on_w   = (const float*)d_in[15];
  const float* on_b   = (const float*)d_in[16];
  const float* head_W = (const float*)d_in[17];
  const float* head_b = (const float*)d_in[18];
  float* out = (float*)d_out;
  WS* ws = (WS*)d_ws;

  // Reset barrier + colsum/xbuf control region; copy initial states into d_out.
  hipMemsetAsync(d_ws, 0, offsetof(WS, ghost), stream);
  hipMemcpyAsync(out + LOGITS, states, sizeof(float) * L * B * H * H,
                 hipMemcpyDeviceToDevice, stream);

  vega_kernel<<<dim3(GRID), dim3(NT), 0, stream>>>(
      ids, emb, nx_w, nx_b, Wp, bp, Wg, Wt, ns_w, ns_b,
      W1, b1, W2, b2, on_w, on_b, head_W, head_b, out, ws);
}

// Round 2
// 13945.110 us; speedup vs baseline: 2.8731x; 2.8731x over previous
//
#include <hip/hip_runtime.h>
#include <hip/hip_bf16.h>
#include <math.h>
#include <stddef.h>

namespace {

constexpr int V = 32000, H = 512, L = 4, A = 384, B = 2, T = 32, FF = 2048;
constexpr long LOGITS = (long)B * T * V;   // 2,048,000
constexpr int NGL = 56;                    // ghost blocks per layer
constexpr int NGHOST = L * NGL;            // 224
constexpr int NXB = 32;                    // x-pipeline blocks (16 t-slots x 2 b)
constexpr int GRID = NGHOST + NXB;         // 256 (1 block/CU)
constexpr int NT = 512;
constexpr float EPS = 1e-5f;

struct WS {
  // ---- flag region (memset to 0 each launch) ----
  unsigned gbar_cnt, gbar_gen;
  unsigned lbar_cnt[L], lbar_gen[L];
  unsigned gcol_cnt[L][T];
  unsigned tok_flag[T][L][B];
  unsigned pad_[64];
  // ---- bulk data (fully written before read) ----
  float gstT[2][L][H][256];      // ghost state, transposed [k][row], ping-pong
  float gcol[L][T][B][H];        // ghost column sums per (l,t,b)
  float asum[T][L][B][H];        // running active colsum token
  float uv[T][L][B][A + H];      // stored u,v per step (epilogue reconstruction)
  float outs[T][B][H];
  float lnouts[T * B][H];        // row = t*2 + b
};

union __align__(16) SMem {
  struct {
    float w[H][20];          // 40.96 KB  weights transposed [k][j2], j2=2*oo+m
    float part[8][10][260];  // 83.2 KB   k-chunk partials [kc][j2][row(pad)]
    float colp[10][B][2];
  } g;
  struct {
    float x[H], lnx[H], p[A + H], h[FF], initcol[L][H], red[8], bu[L];
  } x;  // ~24 KB
  struct { float tile[125][64]; } hd;  // 32 KB
};

__device__ __forceinline__ void fma4(float4& a, const float4& x, float s) {
  a.x = fmaf(x.x, s, a.x); a.y = fmaf(x.y, s, a.y);
  a.z = fmaf(x.z, s, a.z); a.w = fmaf(x.w, s, a.w);
}
__device__ __forceinline__ float dot4(const float4& a, const float4& b) {
  return a.x * b.x + a.y * b.y + a.z * b.z + a.w * b.w;
}

__device__ void barrier_n(unsigned* cnt, unsigned* gen, unsigned n) {
  __syncthreads();
  if (threadIdx.x == 0) {
    __threadfence();
    unsigned g = __hip_atomic_load(gen, __ATOMIC_RELAXED, __HIP_MEMORY_SCOPE_AGENT);
    unsigned a = __hip_atomic_fetch_add(cnt, 1u, __ATOMIC_ACQ_REL, __HIP_MEMORY_SCOPE_AGENT);
    if (a == n - 1) {
      __hip_atomic_store(cnt, 0u, __ATOMIC_RELAXED, __HIP_MEMORY_SCOPE_AGENT);
      __hip_atomic_fetch_add(gen, 1u, __ATOMIC_RELEASE, __HIP_MEMORY_SCOPE_AGENT);
    } else {
      while (__hip_atomic_load(gen, __ATOMIC_ACQUIRE, __HIP_MEMORY_SCOPE_AGENT) == g)
        __builtin_amdgcn_s_sleep(1);
    }
    __threadfence();
  }
  __syncthreads();
}

__device__ float block_reduce(float v, SMem& sm) {
  #pragma unroll
  for (int off = 1; off < 64; off <<= 1) v += __shfl_xor(v, off);
  int wv = threadIdx.x >> 6;
  __syncthreads();
  if ((threadIdx.x & 63) == 0) sm.x.red[wv] = v;
  __syncthreads();
  float s = 0.f;
  #pragma unroll
  for (int q = 0; q < 8; ++q) s += sm.x.red[q];
  return s;
}

// 512-wide layernorm; in/out may be LDS or global row pointers.
__device__ void ln512(SMem& sm, const float* in, float* outp,
                      const float* w, const float* b) {
  int tid = threadIdx.x;
  float xv = in[tid];
  float m = block_reduce(xv, sm) * (1.f / H);
  float d = xv - m;
  float var = block_reduce(d * d, sm) * (1.f / H);
  float inv = rsqrtf(var + EPS);
  outp[tid] = d * inv * w[tid] + b[tid];
  __syncthreads();
}

// ---------------------------------------------------------------- ghost
__device__ void ghost_main(int l, int j, WS* ws, SMem& sm,
                           const float* states, const float* Wg, const float* Wt) {
  const int tid = threadIdx.x;
  const int o0 = (j * H) / NGL, o1 = ((j + 1) * H) / NGL, osz = o1 - o0;  // 9..10
  // W slice -> LDS transposed, zero-pad to 20 lanes-of-j2
  for (int idx = tid; idx < 20 * H; idx += NT) {
    int k = idx / 20, j2 = idx % 20;
    int oo = j2 >> 1, m = j2 & 1;
    float val = 0.f;
    if (oo < osz) {
      const float* Wm = m ? Wt : Wg;
      val = Wm[((long)l * H + (o0 + oo)) * H + k];
    }
    sm.g.w[k][j2] = val;
  }
  // initial transpose of this block's row range into gstT[0]
  int r0 = (j * 256) / NGL, r1 = ((j + 1) * 256) / NGL;
  for (int r = r0; r < r1; ++r) {
    int b = r >> 7, g = r & 127;
    const float* src = states + ((((long)l * B + b) * H) + A + g) * H;
    for (int k = tid; k < H; k += NT) ws->gstT[0][l][k][r] = src[k];
  }
  barrier_n(&ws->lbar_cnt[l], &ws->lbar_gen[l], NGL);

  const int wv = tid >> 6, lane = tid & 63;
  for (int r = 0; r < 64; ++r) {
    const float (*src)[256] = ws->gstT[r & 1][l];
    float (*dst)[256] = ws->gstT[(r & 1) ^ 1][l];
    float4 acc[20];
    #pragma unroll
    for (int q = 0; q < 20; ++q) acc[q] = float4{0.f, 0.f, 0.f, 0.f};
    const int k0 = wv * 64;
    #pragma unroll 4
    for (int k = k0; k < k0 + 64; ++k) {
      const float4 xv = *(const float4*)&src[k][lane * 4];
      const float4* wr = (const float4*)sm.g.w[k];
      float4 w0 = wr[0], w1 = wr[1], w2 = wr[2], w3 = wr[3], w4 = wr[4];
      fma4(acc[0], xv, w0.x); fma4(acc[1], xv, w0.y); fma4(acc[2], xv, w0.z); fma4(acc[3], xv, w0.w);
      fma4(acc[4], xv, w1.x); fma4(acc[5], xv, w1.y); fma4(acc[6], xv, w1.z); fma4(acc[7], xv, w1.w);
      fma4(acc[8], xv, w2.x); fma4(acc[9], xv, w2.y); fma4(acc[10], xv, w2.z); fma4(acc[11], xv, w2.w);
      fma4(acc[12], xv, w3.x); fma4(acc[13], xv, w3.y); fma4(acc[14], xv, w3.z); fma4(acc[15], xv, w3.w);
      fma4(acc[16], xv, w4.x); fma4(acc[17], xv, w4.y); fma4(acc[18], xv, w4.z); fma4(acc[19], xv, w4.w);
    }
    #pragma unroll
    for (int half = 0; half < 2; ++half) {
      __syncthreads();
      #pragma unroll
      for (int j2p = 0; j2p < 10; ++j2p)
        *(float4*)&sm.g.part[wv][j2p][lane * 4] = acc[half * 10 + j2p];
      __syncthreads();
      for (int base = 0; base < 1280; base += NT) {
        int idx = base + tid;
        bool act = idx < 1280;
        int oo_h = idx >> 8, row = idx & 255;
        int oo = half * 5 + oo_h;
        float nv = 0.f;
        if (act && oo < osz) {
          float ag = 0.f, at = 0.f;
          #pragma unroll
          for (int w = 0; w < 8; ++w) {
            ag += sm.g.part[w][2 * oo_h][row];
            at += sm.g.part[w][2 * oo_h + 1][row];
          }
          int o = o0 + oo;
          float upd = (1.f / (1.f + expf(-ag))) * tanhf(at);
          nv = src[o][row] + upd;
          dst[o][row] = nv;
        }
        if (r & 1) {
          float cs = (act && oo < osz) ? nv : 0.f;
          #pragma unroll
          for (int off = 1; off < 64; off <<= 1) cs += __shfl_xor(cs, off);
          if (lane == 0 && act && oo < osz) {
            int b = row >> 7, rh = (row >> 6) & 1;
            sm.g.colp[oo][b][rh] = cs;
          }
        }
      }
    }
    if (r & 1) {
      __syncthreads();
      int t = r >> 1;
      if (tid < osz * B) {
        int oo = tid / B, b = tid % B;
        ws->gcol[l][t][b][o0 + oo] = sm.g.colp[oo][b][0] + sm.g.colp[oo][b][1];
      }
      __threadfence();
      __syncthreads();
      if (tid == 0)
        __hip_atomic_fetch_add(&ws->gcol_cnt[l][t], 1u, __ATOMIC_RELEASE, __HIP_MEMORY_SCOPE_AGENT);
    }
    barrier_n(&ws->lbar_cnt[l], &ws->lbar_gen[l], NGL);
  }
}

// ---------------------------------------------------------------- x-pipeline
__device__ void x_stage(int b, int t, int l, WS* ws, SMem& sm,
                        const float* nx_w, const float* nx_b,
                        const float* Wp, const float* bp,
                        const float* ns_w, const float* ns_b,
                        const float* W1, const float* b1,
                        const float* W2, const float* b2) {
  const int tid = threadIdx.x, wv = tid >> 6, lane = tid & 63;
  // LN1
  ln512(sm, sm.x.x, sm.x.lnx, nx_w + l * H, nx_b + l * H);
  // p = lnx @ Wp[l].T + bp[l]
  {
    float4 xa = *(const float4*)&sm.x.lnx[lane * 8];
    float4 xb = *(const float4*)&sm.x.lnx[lane * 8 + 4];
    for (int out = wv; out < A + H; out += 8) {
      const float4* wr = (const float4*)(Wp + ((long)l * (A + H) + out) * H + lane * 8);
      float pp = dot4(xa, wr[0]) + dot4(xb, wr[1]);
      #pragma unroll
      for (int off = 1; off < 64; off <<= 1) pp += __shfl_xor(pp, off);
      if (lane == 0) sm.x.p[out] = pp + bp[(long)l * (A + H) + out];
    }
    __syncthreads();
  }
  // persist u,v for epilogue
  for (int i = tid; i < A + H; i += NT) ws->uv[t][l][b][i] = sm.x.p[i];
  float U1 = block_reduce(tid < A ? sm.x.p[tid] : 0.f, sm);
  // token t-1 -> t (running active colsum)
  if (t > 0) {
    if (tid == 0)
      while (__hip_atomic_load(&ws->tok_flag[t - 1][l][b], __ATOMIC_ACQUIRE,
                               __HIP_MEMORY_SCOPE_AGENT) == 0)
        __builtin_amdgcn_s_sleep(1);
    __syncthreads();
  }
  float aprev = (t > 0) ? ws->asum[t - 1][l][b][tid] : 0.f;
  float anew = aprev + U1 * sm.x.p[A + tid];
  ws->asum[t][l][b][tid] = anew;
  __threadfence();
  __syncthreads();
  if (tid == 0)
    __hip_atomic_store(&ws->tok_flag[t][l][b], 1u, __ATOMIC_RELEASE, __HIP_MEMORY_SCOPE_AGENT);
  // wait for ghost colsum (l,t)
  if (tid == 0)
    while (__hip_atomic_load(&ws->gcol_cnt[l][t], __ATOMIC_ACQUIRE,
                             __HIP_MEMORY_SCOPE_AGENT) < (unsigned)NGL)
      __builtin_amdgcn_s_sleep(1);
  __syncthreads();
  float gc = ws->gcol[l][t][b][tid];
  float xm = sm.x.x[tid] +
             (anew + sm.x.initcol[l][tid] +
              (float)(t + 1) * sm.x.bu[l] * bp[(long)l * (A + H) + A + tid] + gc) * (1.f / H);
  __syncthreads();
  sm.x.x[tid] = xm;
  __syncthreads();
  // LN2 + FFN
  ln512(sm, sm.x.x, sm.x.lnx, ns_w + l * H, ns_b + l * H);
  {
    float4 xa = *(const float4*)&sm.x.lnx[lane * 8];
    float4 xb = *(const float4*)&sm.x.lnx[lane * 8 + 4];
    for (int out = wv; out < FF; out += 8) {
      const float4* wr = (const float4*)(W1 + ((long)l * FF + out) * H + lane * 8);
      float pp = dot4(xa, wr[0]) + dot4(xb, wr[1]);
      #pragma unroll
      for (int off = 1; off < 64; off <<= 1) pp += __shfl_xor(pp, off);
      if (lane == 0) {
        float z = pp + b1[(long)l * FF + out];
        sm.x.h[out] = 0.5f * z * (1.f + erff(z * 0.70710678118f));
      }
    }
    __syncthreads();
  }
  {
    float4 hc[8];
    #pragma unroll
    for (int q = 0; q < 8; ++q) hc[q] = *(const float4*)&sm.x.h[lane * 32 + q * 4];
    for (int out = wv; out < H; out += 8) {
      const float4* wr = (const float4*)(W2 + ((long)l * H + out) * FF + lane * 32);
      float pp = 0.f;
      #pragma unroll
      for (int q = 0; q < 8; ++q) pp += dot4(hc[q], wr[q]);
      #pragma unroll
      for (int off = 1; off < 64; off <<= 1) pp += __shfl_xor(pp, off);
      if (lane == 0) sm.x.p[out] = pp;
    }
    __syncthreads();
  }
  sm.x.x[tid] = sm.x.x[tid] + sm.x.p[tid] + b2[(long)l * H + tid];
  __syncthreads();
}

// ---------------------------------------------------------------- kernel
__global__ __launch_bounds__(NT, 2) void vega_kernel(
    const int* __restrict__ ids, const float* __restrict__ states,
    const float* __restrict__ emb,
    const float* __restrict__ nx_w, const float* __restrict__ nx_b,
    const float* __restrict__ Wp, const float* __restrict__ bp,
    const float* __restrict__ Wg, const float* __restrict__ Wt,
    const float* __restrict__ ns_w, const float* __restrict__ ns_b,
    const float* __restrict__ W1, const float* __restrict__ b1,
    const float* __restrict__ W2, const float* __restrict__ b2,
    const float* __restrict__ on_w, const float* __restrict__ on_b,
    const float* __restrict__ head_W, const float* __restrict__ head_b,
    float* __restrict__ out, WS* ws) {
  __shared__ SMem sm;
  const int bid = blockIdx.x, tid = threadIdx.x;
  float* fs = out + LOGITS;

  if (bid < NGHOST) {
    ghost_main(bid / NGL, bid % NGL, ws, sm, states, Wg, Wt);
  } else {
    // x-pipeline block
    const int xi = bid - NGHOST, b = xi >> 4, slot = xi & 15;
    for (int l2 = 0; l2 < L; ++l2) {
      float acc = 0.f;
      for (int i = 0; i < A; ++i)
        acc += states[(((long)l2 * B + b) * H + i) * H + tid];
      sm.x.initcol[l2][tid] = acc;
    }
    if (tid < L) {
      float s = 0.f;
      for (int i = 0; i < A; ++i) s += bp[(long)tid * (A + H) + i];
      sm.x.bu[tid] = s;
    }
    __syncthreads();
    for (int tt = 0; tt < 2; ++tt) {
      int t = slot + tt * 16;
      sm.x.x[tid] = emb[(long)ids[b * T + t] * H + tid];
      __syncthreads();
      for (int l = 0; l < L; ++l) {
        x_stage(b, t, l, ws, sm, nx_w, nx_b, Wp, bp, ns_w, ns_b, W1, b1, W2, b2);
        if (l == L - 1) { ws->outs[t][b][tid] = sm.x.x[tid]; }
      }
    }
  }

  barrier_n(&ws->gbar_cnt, &ws->gbar_gen, GRID);

  // -------- E1: fstates + final LN of outs --------
  if (bid < 192) {
    int lb = bid / 24, sub = bid % 24;
    int l = lb >> 1, b = lb & 1, r0 = sub * 16;
    long base = (long)l * (A + H);
    for (int rr = 0; rr < 16; ++rr) {
      int i = r0 + rr;
      float acc = states[(((long)l * B + b) * H + i) * H + tid] +
                  32.f * bp[base + i] * bp[base + A + tid];
      for (int t2 = 0; t2 < T; ++t2)
        acc += ws->uv[t2][l][b][i] * ws->uv[t2][l][b][A + tid];
      fs[(((long)l * B + b) * H + i) * H + tid] = acc;
    }
  } else {
    int idx = bid - 192, lb = idx / 8, sub = idx % 8;
    int l = lb >> 1, b = lb & 1, g0 = sub * 16;
    for (int gg = 0; gg < 16; ++gg) {
      int g = g0 + gg;
      for (int k = tid; k < H; k += NT)
        fs[(((long)l * B + b) * H + A + g) * H + k] = ws->gstT[0][l][k][b * 128 + g];
    }
  }
  if (bid < T * B) {
    int row = bid, t = row >> 1, b = row & 1;
    ln512(sm, ws->outs[t][b], ws->lnouts[row], on_w, on_b);
  }

  barrier_n(&ws->gbar_cnt, &ws->gbar_gen, GRID);

  // -------- E2: head GEMM (64 rows x 125 vocab per block, K=512) --------
  {
    const int wv = tid >> 6, lane = tid & 63;
    const long vbase = (long)bid * 125;
    float acc[16];
    #pragma unroll
    for (int q = 0; q < 16; ++q) acc[q] = 0.f;
    for (int c = 0; c < 8; ++c) {
      float4 xr[16];
      #pragma unroll
      for (int q = 0; q < 16; ++q)
        xr[q] = *(const float4*)&ws->lnouts[lane][c * 64 + q * 4];
      #pragma unroll
      for (int vi = 0; vi < 16; ++vi) {
        int vloc = vi * 8 + wv;
        if (vloc < 125) {
          const float4* wp_ = (const float4*)(head_W + (vbase + vloc) * H + c * 64);
          float s = 0.f;
          #pragma unroll
          for (int q = 0; q < 16; ++q) s += dot4(xr[q], wp_[q]);
          acc[vi] += s;
        }
      }
    }
    #pragma unroll
    for (int vi = 0; vi < 16; ++vi) {
      int vloc = vi * 8 + wv;
      if (vloc < 125) sm.hd.tile[vloc][lane] = acc[vi] + head_b[vbase + vloc];
    }
    __syncthreads();
    for (int idx = tid; idx < 64 * 125; idx += NT) {
      int row = idx / 125, vl = idx % 125;
      int t = row >> 1, b = row & 1;
      out[((long)(b * T + t)) * V + vbase + vl] = sm.hd.tile[vl][row];
    }
  }
}

}  // namespace

extern "C" void kernel_launch(void* const* d_in, const int* in_sizes, int n_in,
                              void* d_out, int out_size, void* d_ws, size_t ws_size,
                              hipStream_t stream) {
  (void)in_sizes; (void)n_in; (void)out_size; (void)ws_size;
  const int*   ids    = (const int*)d_in[0];
  const float* states = (const float*)d_in[1];
  const float* emb    = (const float*)d_in[2];
  const float* nx_w   = (const float*)d_in[3];
  const float* nx_b   = (const float*)d_in[4];
  const float* Wp     = (const float*)d_in[5];
  const float* bp     = (const float*)d_in[6];
  const float* Wg     = (const float*)d_in[7];
  const float* Wt     = (const float*)d_in[8];
  const float* ns_w   = (const float*)d_in[9];
  const float* ns_b   = (const float*)d_in[10];
  const float* W1     = (const float*)d_in[11];
  const float* b1     = (const float*)d_in[12];
  const float* W2     = (const float*)d_in[13];
  const float* b2     = (const float*)d_in[14];
  const float* on_w   = (const float*)d_in[15];
  const float* on_b   = (const float*)d_in[16];
  const float* head_W = (const float*)d_in[17];
  const float* head_b = (const float*)d_in[18];
  float* out = (float*)d_out;
  WS* ws = (WS*)d_ws;

  hipMemsetAsync(d_ws, 0, offsetof(WS, gstT), stream);
  vega_kernel<<<dim3(GRID), dim3(NT), 0, stream>>>(
      ids, states, emb, nx_w, nx_b, Wp, bp, Wg, Wt, ns_w, ns_b,
      W1, b1, W2, b2, on_w, on_b, head_W, head_b, out, ws);
}

// Round 4
// 4439.703 us; speedup vs baseline: 9.0245x; 3.1410x over previous
//
#include <hip/hip_runtime.h>
#include <hip/hip_bf16.h>
#include <math.h>
#include <stddef.h>

namespace {

constexpr int V = 32000, H = 512, L = 4, A = 384, B = 2, T = 32, FF = 2048;
constexpr long LOGITS = (long)B * T * V;   // 2,048,000
constexpr int GRID = 256, NT = 512;
constexpr int NBG = 22;                    // ghost blocks per (l,b)
constexpr float EPS = 1e-5f;

struct WS {
  // ---- zeroed region ----
  unsigned gbar_cnt, gbar_gen;
  unsigned pad0[62];
  unsigned gcol_cnt[L][T][B];
  unsigned tok_flag[T][L][B];
  unsigned pad1[64];
  float gcol[L][T][B][H];        // 512 KB, atomicAdd accumulated
  // ---- not zeroed (written before read every launch) ----
  float asum[T][L][B][H];
  float uv[T][L][B][A + H];
  float outs[T][B][H];
  float lnouts[T * B][H];
  float wgtf[L][H / 4][2][H][4]; // f32, [l][k4][m(g,t)][o][k%4] — 8 MB
};

union __align__(16) SMem {
  struct { float s[6][H]; } g;                                                      // 12 KB
  struct { float x[H], lnx[H], p[A + H], h[FF], initcol[L][H], red[8], bu[L]; } x;  // ~24 KB
  struct { float tile[125][64]; } hd;                                               // 32 KB
};

__device__ __forceinline__ float dot4(const float4& a, const float4& b) {
  return a.x * b.x + a.y * b.y + a.z * b.z + a.w * b.w;
}

__device__ __forceinline__ void wait_u32(unsigned* p, unsigned target) {
  int spin = 0;
  while (__hip_atomic_load(p, __ATOMIC_RELAXED, __HIP_MEMORY_SCOPE_AGENT) < target) {
    __builtin_amdgcn_s_sleep(8);
    if ((++spin & 63) == 0)  // deadlock backstop
      (void)__hip_atomic_load(p, __ATOMIC_ACQUIRE, __HIP_MEMORY_SCOPE_AGENT);
  }
}

__device__ void gbar(WS* ws) {
  __syncthreads();
  if (threadIdx.x == 0) {
    __threadfence();
    unsigned g = __hip_atomic_load(&ws->gbar_gen, __ATOMIC_RELAXED, __HIP_MEMORY_SCOPE_AGENT);
    unsigned a = __hip_atomic_fetch_add(&ws->gbar_cnt, 1u, __ATOMIC_ACQ_REL, __HIP_MEMORY_SCOPE_AGENT);
    if (a == (unsigned)(GRID - 1)) {
      __hip_atomic_store(&ws->gbar_cnt, 0u, __ATOMIC_RELAXED, __HIP_MEMORY_SCOPE_AGENT);
      __hip_atomic_fetch_add(&ws->gbar_gen, 1u, __ATOMIC_RELEASE, __HIP_MEMORY_SCOPE_AGENT);
    } else {
      wait_u32(&ws->gbar_gen, g + 1);
    }
    __threadfence();
  }
  __syncthreads();
}

__device__ float block_reduce(float v, SMem& sm) {
  #pragma unroll
  for (int off = 1; off < 64; off <<= 1) v += __shfl_xor(v, off);
  int wv = threadIdx.x >> 6;
  __syncthreads();
  if ((threadIdx.x & 63) == 0) sm.x.red[wv] = v;
  __syncthreads();
  float s = 0.f;
  #pragma unroll
  for (int q = 0; q < 8; ++q) s += sm.x.red[q];
  return s;
}

__device__ void ln512(SMem& sm, const float* in, float* outp,
                      const float* w, const float* b) {
  int tid = threadIdx.x;
  float xv = in[tid];
  float m = block_reduce(xv, sm) * (1.f / H);
  float d = xv - m;
  float var = block_reduce(d * d, sm) * (1.f / H);
  float inv = rsqrtf(var + EPS);
  outp[tid] = d * inv * w[tid] + b[tid];
  __syncthreads();
}

// ---------------------------------------------------------------- ghost
// Block owns R rows of one (l,b); state in LDS; f32 weights streamed from L2;
// zero inter-block sync (each ghost row's recurrence is independent).
template <int R>
__device__ void ghost_loop(int l, int b, int r0, WS* ws, SMem& sm,
                           const float* __restrict__ states, float* __restrict__ fs) {
  const int tid = threadIdx.x;
  for (int r = 0; r < R; ++r)
    sm.g.s[r][tid] = states[((((long)l * B + b) * H) + A + r0 + r) * H + tid];
  __syncthreads();
  const float4* __restrict__ Wf = (const float4*)ws->wgtf + (long)l * 128 * 2 * 512;

  for (int rec = 0; rec < 2 * T; ++rec) {
    float ag[R], at_[R];
    #pragma unroll
    for (int r = 0; r < R; ++r) { ag[r] = 0.f; at_[r] = 0.f; }
    #pragma unroll 2
    for (int k4 = 0; k4 < 128; ++k4) {
      float4 wg = Wf[(k4 * 2 + 0) * 512 + tid];
      float4 wt = Wf[(k4 * 2 + 1) * 512 + tid];
      #pragma unroll
      for (int r = 0; r < R; ++r) {
        float4 sv = *(const float4*)&sm.g.s[r][k4 * 4];  // wave-uniform: LDS broadcast
        ag[r]  = fmaf(sv.x, wg.x, fmaf(sv.y, wg.y, fmaf(sv.z, wg.z, fmaf(sv.w, wg.w, ag[r]))));
        at_[r] = fmaf(sv.x, wt.x, fmaf(sv.y, wt.y, fmaf(sv.z, wt.z, fmaf(sv.w, wt.w, at_[r]))));
      }
    }
    float upd[R];
    #pragma unroll
    for (int r = 0; r < R; ++r)
      upd[r] = tanhf(at_[r]) * (1.f / (1.f + expf(-ag[r])));
    __syncthreads();
    #pragma unroll
    for (int r = 0; r < R; ++r) sm.g.s[r][tid] += upd[r];
    __syncthreads();

    if (rec & 1) {  // publish colsum for t = rec>>1
      int t = rec >> 1;
      float cs = 0.f;
      #pragma unroll
      for (int r = 0; r < R; ++r) cs += sm.g.s[r][tid];
      __hip_atomic_fetch_add(&ws->gcol[l][t][b][tid], cs,
                             __ATOMIC_RELAXED, __HIP_MEMORY_SCOPE_AGENT);
      __builtin_amdgcn_s_waitcnt(0);   // this wave's atomic issued & acked
      __syncthreads();                 // all waves acked
      if (tid == 0)
        __hip_atomic_fetch_add(&ws->gcol_cnt[l][t][b], 1u,
                               __ATOMIC_RELEASE, __HIP_MEMORY_SCOPE_AGENT);
    }
  }
  for (int r = 0; r < R; ++r)
    fs[((((long)l * B + b) * H) + A + r0 + r) * H + tid] = sm.g.s[r][tid];
}

// ---------------------------------------------------------------- x-pipeline
__device__ void x_stage(int b, int t, int l, WS* ws, SMem& sm,
                        const float* nx_w, const float* nx_b,
                        const float* Wp, const float* bp,
                        const float* ns_w, const float* ns_b,
                        const float* W1, const float* b1,
                        const float* W2, const float* b2) {
  const int tid = threadIdx.x, wv = tid >> 6, lane = tid & 63;
  ln512(sm, sm.x.x, sm.x.lnx, nx_w + l * H, nx_b + l * H);
  {
    float4 xa = *(const float4*)&sm.x.lnx[lane * 8];
    float4 xb = *(const float4*)&sm.x.lnx[lane * 8 + 4];
    for (int o = wv; o < A + H; o += 8) {
      const float4* wr = (const float4*)(Wp + ((long)l * (A + H) + o) * H + lane * 8);
      float pp = dot4(xa, wr[0]) + dot4(xb, wr[1]);
      #pragma unroll
      for (int off = 1; off < 64; off <<= 1) pp += __shfl_xor(pp, off);
      if (lane == 0) sm.x.p[o] = pp + bp[(long)l * (A + H) + o];
    }
    __syncthreads();
  }
  for (int i = tid; i < A + H; i += NT) ws->uv[t][l][b][i] = sm.x.p[i];
  float U1 = block_reduce(tid < A ? sm.x.p[tid] : 0.f, sm);
  // token chain t-1 -> t (pure atomic channel)
  if (t > 0) {
    if (tid == 0) wait_u32(&ws->tok_flag[t - 1][l][b], 1u);
    __syncthreads();
  }
  float aprev = (t > 0)
      ? __hip_atomic_load(&ws->asum[t - 1][l][b][tid], __ATOMIC_RELAXED, __HIP_MEMORY_SCOPE_AGENT)
      : 0.f;
  float anew = aprev + U1 * sm.x.p[A + tid];
  __hip_atomic_store(&ws->asum[t][l][b][tid], anew, __ATOMIC_RELAXED, __HIP_MEMORY_SCOPE_AGENT);
  __builtin_amdgcn_s_waitcnt(0);
  __syncthreads();
  if (tid == 0)
    __hip_atomic_store(&ws->tok_flag[t][l][b], 1u, __ATOMIC_RELEASE, __HIP_MEMORY_SCOPE_AGENT);
  // ghost colsum wait
  if (tid == 0) wait_u32(&ws->gcol_cnt[l][t][b], (unsigned)NBG);
  __syncthreads();
  float gc = __hip_atomic_load(&ws->gcol[l][t][b][tid], __ATOMIC_RELAXED, __HIP_MEMORY_SCOPE_AGENT);
  float xm = sm.x.x[tid] +
             (anew + sm.x.initcol[l][tid] +
              (float)(t + 1) * sm.x.bu[l] * bp[(long)l * (A + H) + A + tid] + gc) * (1.f / H);
  __syncthreads();
  sm.x.x[tid] = xm;
  __syncthreads();
  ln512(sm, sm.x.x, sm.x.lnx, ns_w + l * H, ns_b + l * H);
  {
    float4 xa = *(const float4*)&sm.x.lnx[lane * 8];
    float4 xb = *(const float4*)&sm.x.lnx[lane * 8 + 4];
    for (int o = wv; o < FF; o += 8) {
      const float4* wr = (const float4*)(W1 + ((long)l * FF + o) * H + lane * 8);
      float pp = dot4(xa, wr[0]) + dot4(xb, wr[1]);
      #pragma unroll
      for (int off = 1; off < 64; off <<= 1) pp += __shfl_xor(pp, off);
      if (lane == 0) {
        float z = pp + b1[(long)l * FF + o];
        sm.x.h[o] = 0.5f * z * (1.f + erff(z * 0.70710678118f));
      }
    }
    __syncthreads();
  }
  {
    float4 hc[8];
    #pragma unroll
    for (int q = 0; q < 8; ++q) hc[q] = *(const float4*)&sm.x.h[lane * 32 + q * 4];
    for (int o = wv; o < H; o += 8) {
      const float4* wr = (const float4*)(W2 + ((long)l * H + o) * FF + lane * 32);
      float pp = 0.f;
      #pragma unroll
      for (int q = 0; q < 8; ++q) pp += dot4(hc[q], wr[q]);
      #pragma unroll
      for (int off = 1; off < 64; off <<= 1) pp += __shfl_xor(pp, off);
      if (lane == 0) sm.x.p[o] = pp;
    }
    __syncthreads();
  }
  sm.x.x[tid] = sm.x.x[tid] + sm.x.p[tid] + b2[(long)l * H + tid];
  __syncthreads();
}

// ---------------------------------------------------------------- prologue pack (f32)
__global__ __launch_bounds__(256) void pack_wgt_kernel(const float* __restrict__ Wg,
                                                       const float* __restrict__ Wt, WS* ws) {
  __shared__ float gg[32][33], tt[32][33];
  int bid = blockIdx.x;                       // L*16*16 = 1024
  int l = bid >> 8, rem = bid & 255, kt = rem >> 4, ot = rem & 15;
  int tx = threadIdx.x & 31, ty = threadIdx.x >> 5;  // tx 0..31, ty 0..7
  for (int i0 = 0; i0 < 32; i0 += 8) {
    int o = ot * 32 + ty + i0, k = kt * 32 + tx;
    gg[ty + i0][tx] = Wg[((long)l * H + o) * H + k];   // gg[o_l][k_l]
    tt[ty + i0][tx] = Wt[((long)l * H + o) * H + k];
  }
  __syncthreads();
  int k4 = kt * 8 + ty, o = ot * 32 + tx;
  float4 vg, vt;
  vg.x = gg[tx][ty * 4 + 0]; vg.y = gg[tx][ty * 4 + 1];
  vg.z = gg[tx][ty * 4 + 2]; vg.w = gg[tx][ty * 4 + 3];
  vt.x = tt[tx][ty * 4 + 0]; vt.y = tt[tx][ty * 4 + 1];
  vt.z = tt[tx][ty * 4 + 2]; vt.w = tt[tx][ty * 4 + 3];
  float4* dst = (float4*)ws->wgtf;
  dst[(((long)l * 128 + k4) * 2 + 0) * 512 + o] = vg;
  dst[(((long)l * 128 + k4) * 2 + 1) * 512 + o] = vt;
}

// ---------------------------------------------------------------- main kernel
__global__ __launch_bounds__(NT, 1) void vega_kernel(
    const int* __restrict__ ids, const float* __restrict__ states,
    const float* __restrict__ emb,
    const float* __restrict__ nx_w, const float* __restrict__ nx_b,
    const float* __restrict__ Wp, const float* __restrict__ bp,
    const float* __restrict__ ns_w, const float* __restrict__ ns_b,
    const float* __restrict__ W1, const float* __restrict__ b1,
    const float* __restrict__ W2, const float* __restrict__ b2,
    const float* __restrict__ on_w, const float* __restrict__ on_b,
    const float* __restrict__ head_W, const float* __restrict__ head_b,
    float* __restrict__ out, WS* ws) {
  __shared__ SMem sm;
  const int bid = blockIdx.x, tid = threadIdx.x;
  float* fs = out + LOGITS;

  const int xcd = bid & 7, sl = bid >> 3;
  if (sl < NBG) {
    // ghost: (l,b) pinned to XCD so the 2 MB f32 weight stream stays L2-resident
    int l = xcd >> 1, b = xcd & 1, j = sl;
    int r0 = (j * 128) / NBG, r1 = ((j + 1) * 128) / NBG;
    if (r1 - r0 == 5) ghost_loop<5>(l, b, r0, ws, sm, states, fs);
    else              ghost_loop<6>(l, b, r0, ws, sm, states, fs);
  } else if (sl < 26) {
    int xi = (sl - NBG) * 8 + xcd;  // 0..31
    int b = xi >> 4, slot = xi & 15;
    #pragma unroll 1
    for (int l2 = 0; l2 < L; ++l2) {
      float acc = 0.f;
      #pragma unroll 4
      for (int i = 0; i < A; ++i)
        acc += states[(((long)l2 * B + b) * H + i) * H + tid];
      sm.x.initcol[l2][tid] = acc;
    }
    if (tid < L) {
      float s = 0.f;
      for (int i = 0; i < A; ++i) s += bp[(long)tid * (A + H) + i];
      sm.x.bu[tid] = s;
    }
    __syncthreads();
    for (int tt = 0; tt < 2; ++tt) {
      int t = slot + tt * 16;
      sm.x.x[tid] = emb[(long)ids[b * T + t] * H + tid];
      __syncthreads();
      for (int l = 0; l < L; ++l) {
        x_stage(b, t, l, ws, sm, nx_w, nx_b, Wp, bp, ns_w, ns_b, W1, b1, W2, b2);
        if (l == L - 1) ws->outs[t][b][tid] = sm.x.x[tid];
      }
    }
  }
  // sl in [26,32): idle workers — fall through to epilogue

  gbar(ws);

  // -------- E1: active fstates reconstruction + final LN of outs --------
  if (bid < 192) {
    int lb = bid / 24, sub = bid % 24;
    int l = lb >> 1, b = lb & 1, r0 = sub * 16;
    long base = (long)l * (A + H);
    float bv = bp[base + A + tid];
    float acc[16];
    #pragma unroll
    for (int q = 0; q < 16; ++q) acc[q] = 32.f * bp[base + r0 + q] * bv;
    for (int t2 = 0; t2 < T; ++t2) {
      float vv = ws->uv[t2][l][b][A + tid];
      const float* u = &ws->uv[t2][l][b][0];
      #pragma unroll
      for (int q = 0; q < 16; ++q) acc[q] = fmaf(u[r0 + q], vv, acc[q]);
    }
    #pragma unroll
    for (int q = 0; q < 16; ++q)
      fs[(((long)l * B + b) * H + (r0 + q)) * H + tid] =
          states[(((long)l * B + b) * H + (r0 + q)) * H + tid] + acc[q];
  }
  if (bid < T * B) {
    int row = bid, t = row >> 1, b = row & 1;
    ln512(sm, ws->outs[t][b], ws->lnouts[row], on_w, on_b);
  }

  gbar(ws);

  // -------- E2: head GEMM (64 rows x 125 vocab per block, K=512) --------
  {
    const int wv = tid >> 6, lane = tid & 63;
    const long vbase = (long)bid * 125;
    float acc[16];
    #pragma unroll
    for (int q = 0; q < 16; ++q) acc[q] = 0.f;
    for (int c = 0; c < 8; ++c) {
      float4 xr[16];
      #pragma unroll
      for (int q = 0; q < 16; ++q)
        xr[q] = *(const float4*)&ws->lnouts[lane][c * 64 + q * 4];
      #pragma unroll
      for (int vi = 0; vi < 16; ++vi) {
        int vloc = vi * 8 + wv;
        if (vloc < 125) {
          const float4* wp_ = (const float4*)(head_W + (vbase + vloc) * H + c * 64);
          float s = 0.f;
          #pragma unroll
          for (int q = 0; q < 16; ++q) s += dot4(xr[q], wp_[q]);
          acc[vi] += s;
        }
      }
    }
    #pragma unroll
    for (int vi = 0; vi < 16; ++vi) {
      int vloc = vi * 8 + wv;
      if (vloc < 125) sm.hd.tile[vloc][lane] = acc[vi] + head_b[vbase + vloc];
    }
    __syncthreads();
    for (int idx = tid; idx < 64 * 125; idx += NT) {
      int row = idx / 125, vl = idx % 125;
      int t = row >> 1, b = row & 1;
      out[((long)(b * T + t)) * V + vbase + vl] = sm.hd.tile[vl][row];
    }
  }
}

}  // namespace

extern "C" void kernel_launch(void* const* d_in, const int* in_sizes, int n_in,
                              void* d_out, int out_size, void* d_ws, size_t ws_size,
                              hipStream_t stream) {
  (void)in_sizes; (void)n_in; (void)out_size; (void)ws_size;
  const int*   ids    = (const int*)d_in[0];
  const float* states = (const float*)d_in[1];
  const float* emb    = (const float*)d_in[2];
  const float* nx_w   = (const float*)d_in[3];
  const float* nx_b   = (const float*)d_in[4];
  const float* Wp     = (const float*)d_in[5];
  const float* bp     = (const float*)d_in[6];
  const float* Wg     = (const float*)d_in[7];
  const float* Wt     = (const float*)d_in[8];
  const float* ns_w   = (const float*)d_in[9];
  const float* ns_b   = (const float*)d_in[10];
  const float* W1     = (const float*)d_in[11];
  const float* b1     = (const float*)d_in[12];
  const float* W2     = (const float*)d_in[13];
  const float* b2     = (const float*)d_in[14];
  const float* on_w   = (const float*)d_in[15];
  const float* on_b   = (const float*)d_in[16];
  const float* head_W = (const float*)d_in[17];
  const float* head_b = (const float*)d_in[18];
  float* out = (float*)d_out;
  WS* ws = (WS*)d_ws;

  hipMemsetAsync(d_ws, 0, offsetof(WS, asum), stream);
  pack_wgt_kernel<<<dim3(1024), dim3(256), 0, stream>>>(Wg, Wt, ws);
  vega_kernel<<<dim3(GRID), dim3(NT), 0, stream>>>(
      ids, states, emb, nx_w, nx_b, Wp, bp, ns_w, ns_b,
      W1, b1, W2, b2, on_w, on_b, head_W, head_b, out, ws);
}